// Round 14
// baseline (50.041 us; speedup 1.0000x reference)
//
#include <hip/hip_runtime.h>

#define Ndim 128
#define Cdim 3
#define Hdim 256
#define Wdim 256
#define HW (Hdim * Wdim)
#define MAXNORM_F 5.371920351148152f

#define LCOLS 56     // staged window width (14 x 16B chunks)
#define LROWS 48     // staged window max rows (guard rn <= 48)
#define LBUF  (LCOLS * LROWS)   // 2688 dwords = 10752 B per channel buffer

typedef unsigned int uint32;

__device__ __forceinline__ void mm3f(const float a[3][3], const float b[3][3], float c[3][3]) {
    #pragma unroll
    for (int i = 0; i < 3; ++i)
        #pragma unroll
        for (int j = 0; j < 3; ++j) {
            float s = 0.0f;
            #pragma unroll
            for (int k = 0; k < 3; ++k) s = fmaf(a[i][k], b[k][j], s);
            c[i][j] = s;
        }
}

// One thread per batch element: expm of padded 3x3 affine matrix (fp32 Pade-13).
__global__ void expm_kernel(const float* __restrict__ theta, float* __restrict__ thOut) {
    int n = blockIdx.x * blockDim.x + threadIdx.x;
    if (n >= Ndim) return;

    const float b[14] = {6.476475253248e+16f, 3.238237626624e+16f, 7771770303897600.0f,
                         1187353796428800.0f, 129060195264000.0f, 10559470521600.0f,
                         670442572800.0f, 33522128640.0f, 1323241920.0f, 40840800.0f,
                         960960.0f, 16380.0f, 182.0f, 1.0f};

    float A[3][3];
    #pragma unroll
    for (int j = 0; j < 3; ++j) {
        A[0][j] = theta[n * 6 + j];
        A[1][j] = theta[n * 6 + 3 + j];
        A[2][j] = 0.0f;
    }

    float fro2 = 0.0f;
    #pragma unroll
    for (int i = 0; i < 3; ++i)
        #pragma unroll
        for (int j = 0; j < 3; ++j) fro2 = fmaf(A[i][j], A[i][j], fro2);
    float fro = sqrtf(fro2);

    float nsq = fmaxf(0.0f, ceilf(log2f(fro / MAXNORM_F)));
    int k = (int)nsq;
    float sc = exp2f(-nsq);
    #pragma unroll
    for (int i = 0; i < 3; ++i)
        #pragma unroll
        for (int j = 0; j < 3; ++j) A[i][j] *= sc;

    float A2[3][3], A4[3][3], A6[3][3], P[3][3], Wm[3][3], T[3][3], U[3][3], V[3][3];
    mm3f(A, A, A2);
    mm3f(A2, A2, A4);
    mm3f(A4, A2, A6);

    #pragma unroll
    for (int i = 0; i < 3; ++i)
        #pragma unroll
        for (int j = 0; j < 3; ++j)
            P[i][j] = b[13] * A6[i][j] + b[11] * A4[i][j] + b[9] * A2[i][j];
    mm3f(A6, P, T);
    #pragma unroll
    for (int i = 0; i < 3; ++i)
        #pragma unroll
        for (int j = 0; j < 3; ++j)
            Wm[i][j] = T[i][j] + b[7] * A6[i][j] + b[5] * A4[i][j] + b[3] * A2[i][j]
                       + (i == j ? b[1] : 0.0f);
    mm3f(A, Wm, U);

    #pragma unroll
    for (int i = 0; i < 3; ++i)
        #pragma unroll
        for (int j = 0; j < 3; ++j)
            P[i][j] = b[12] * A6[i][j] + b[10] * A4[i][j] + b[8] * A2[i][j];
    mm3f(A6, P, T);
    #pragma unroll
    for (int i = 0; i < 3; ++i)
        #pragma unroll
        for (int j = 0; j < 3; ++j)
            V[i][j] = T[i][j] + b[6] * A6[i][j] + b[4] * A4[i][j] + b[2] * A2[i][j]
                      + (i == j ? b[0] : 0.0f);

    float M[3][6];
    #pragma unroll
    for (int i = 0; i < 3; ++i)
        #pragma unroll
        for (int j = 0; j < 3; ++j) {
            M[i][j]     = U[i][j] + V[i][j];
            M[i][j + 3] = V[i][j] - U[i][j];
        }
    #pragma unroll
    for (int col = 0; col < 3; ++col) {
        int piv = col;
        float best = fabsf(M[col][col]);
        for (int r = col + 1; r < 3; ++r) {
            float v = fabsf(M[r][col]);
            if (v > best) { best = v; piv = r; }
        }
        if (piv != col) {
            #pragma unroll
            for (int j = 0; j < 6; ++j) {
                float t = M[col][j]; M[col][j] = M[piv][j]; M[piv][j] = t;
            }
        }
        float inv = 1.0f / M[col][col];
        #pragma unroll
        for (int j = 0; j < 6; ++j) M[col][j] *= inv;
        #pragma unroll
        for (int r = 0; r < 3; ++r) {
            if (r == col) continue;
            float f = M[r][col];
            #pragma unroll
            for (int j = 0; j < 6; ++j) M[r][j] -= f * M[col][j];
        }
    }
    float R[3][3];
    #pragma unroll
    for (int i = 0; i < 3; ++i)
        #pragma unroll
        for (int j = 0; j < 3; ++j) R[i][j] = M[i][j + 3];

    for (int i = 0; i < 16; ++i) {
        if (i < k) {
            float Rn[3][3];
            mm3f(R, R, Rn);
            #pragma unroll
            for (int a = 0; a < 3; ++a)
                #pragma unroll
                for (int c = 0; c < 3; ++c) R[a][c] = Rn[a][c];
        }
    }

    #pragma unroll
    for (int j = 0; j < 3; ++j) {
        thOut[n * 6 + j]     = (float)R[0][j];
        thOut[n * 6 + 3 + j] = (float)R[1][j];
    }
}

__device__ __forceinline__ void stage_ch(const float* __restrict__ gch, int bxw, int byw,
                                         int rn, float* __restrict__ buf, int tid) {
    int totc = 14 * rn;   // <= 672
    #pragma unroll
    for (int it = 0; it < 3; ++it) {
        int k = (it << 8) + tid;
        if (k < totc) {
            int row = k / 14;
            int col = k - row * 14;
            const float* gp = gch + ((byw + row) << 8) + bxw + (col << 2);
            __builtin_amdgcn_global_load_lds(
                (const __attribute__((address_space(1))) uint32*)gp,
                (__attribute__((address_space(3))) uint32*)((uint32*)buf + ((size_t)k << 2)),
                16, 0, 0);
        }
    }
}

// Fused affine_grid + bilinear grid_sample (zeros padding, align_corners=True).
// R14: each block processes FOUR vertically-consecutive 32x32 tiles of one
// image column as one continuous ping-pong pipeline over 12 stage/sample
// units (unit u = tile u/3, channel u%3, buffer u&1):
//   stage(u0); { bar; stage(u+1); sample(u); } x12
// Pipeline-fill latency (stage->vmcnt-drain) is exposed once per 12 units
// instead of once per 3 (R13): exposure events 8192 -> 2048. Same tiles,
// same LDS (21504B), same read geometry. Threads: 1x4 strip per tile,
// lane-consecutive columns (conflict-benign). Interior tiles mask/clamp-free;
// edge tiles per-corner-clamped; any tile failing the window guard sends the
// whole block down a sequential exact path (block-uniform).
__global__ __launch_bounds__(256) void sample_kernel(const float* __restrict__ x,
                                                     const float* __restrict__ th,
                                                     float* __restrict__ out) {
    __shared__ float lds[2][LBUF];

    // 8 (w-tiles) x 2 (tile-groups) x 128 images = 2048 blocks; XCD swizzle
    const int nwg_per_xcd = 2048 / 8;
    int bid = blockIdx.x;
    int wgid = (bid & 7) * nwg_per_xcd + (bid >> 3);

    int tw  = wgid & 7;
    int thg = (wgid >> 3) & 1;   // group of 4 h-tiles
    int n   = wgid >> 4;

    int tid = threadIdx.x;
    int w = (tw << 5) + (tid & 31);          // lane-consecutive column

    const float* t = th + n * 6;
    float t0 = t[0], t1 = t[1], t2 = t[2], t3 = t[3], t4 = t[4], t5 = t[5];

    float Cx = 127.5f * (t2 - t0 - t1 + 1.0f);
    float Cy = 127.5f * (t5 - t3 - t4 + 1.0f);

    float fwA = (float)(tw << 5), fwB = fwA + 31.0f;

    // per-tile block-uniform windows
    int bxws[4], byws[4], rns[4];
    bool inters[4], fasts[4];
    bool fastAll = true;
    #pragma unroll
    for (int tt = 0; tt < 4; ++tt) {
        int thp = (thg << 2) + tt;
        float fhA = (float)(thp << 5), fhB = fhA + 31.0f;
        float xlo = fminf(fwA * t0, fwB * t0) + fminf(fhA * t1, fhB * t1) + Cx;
        float xhi = fmaxf(fwA * t0, fwB * t0) + fmaxf(fhA * t1, fhB * t1) + Cx;
        float ylo = fminf(fwA * t3, fwB * t3) + fminf(fhA * t4, fhB * t4) + Cy;
        float yhi = fmaxf(fwA * t3, fwB * t3) + fmaxf(fhA * t4, fhB * t4) + Cy;
        int Xlo = (int)floorf(xlo) - 1, Xhi = (int)floorf(xhi) + 2;
        int Ylo = (int)floorf(ylo) - 1, Yhi = (int)floorf(yhi) + 2;
        int cn = Xhi - Xlo + 1;
        int rn = Yhi - Ylo + 1;
        rn = min(max(rn, 1), 200);
        bool f = (cn <= 52) && (cn >= 1) && (rn <= LROWS);
        fasts[tt] = f;
        fastAll &= f;
        bxws[tt] = (min(max(Xlo, 0), Wdim - LCOLS)) & ~3;
        byws[tt] = min(max(Ylo, 0), Hdim - rn);
        rns[tt]  = rn;
        inters[tt] = (Xlo >= 0) && (Xhi <= Wdim - 1) && (Ylo >= 0) && (Yhi <= Hdim - 1);
    }

    size_t nbase = (size_t)n * Cdim * HW;
    const float* gbase = x + nbase;

    if (fastAll) {
        stage_ch(gbase, bxws[0], byws[0], rns[0], lds[0], tid);   // unit 0: t0,c0,buf0

        #pragma unroll
        for (int tt = 0; tt < 4; ++tt) {
            int thp = (thg << 2) + tt;
            int h0 = (thp << 5) + ((tid >> 5) << 2);
            int bxw = bxws[tt], byw = byws[tt], rn = rns[tt];
            bool inter = inters[tt];

            // strip coords for 4 px
            float ixs[4], iys[4];
            float ixb = fmaf((float)w, t0, fmaf((float)h0, t1, Cx));
            float iyb = fmaf((float)w, t3, fmaf((float)h0, t4, Cy));
            #pragma unroll
            for (int p = 0; p < 4; ++p) {
                ixs[p] = fmaf((float)p, t1, ixb);
                iys[p] = fmaf((float)p, t4, iyb);
            }

            int   basev[4];
            float wx1v[4], wx0v[4], wy1v[4], wy0v[4];
            if (inter) {
                #pragma unroll
                for (int p = 0; p < 4; ++p) {
                    float fx = floorf(ixs[p]), fy = floorf(iys[p]);
                    wx1v[p] = ixs[p] - fx; wx0v[p] = 1.0f - wx1v[p];
                    wy1v[p] = iys[p] - fy; wy0v[p] = 1.0f - wy1v[p];
                    basev[p] = ((int)fy - byw) * LCOLS + ((int)fx - bxw);
                }
            }
            size_t p0 = (size_t)h0 * Wdim + w;

            auto sampleI = [&](int buf, int c) {
                float* o = out + nbase + (size_t)c * HW + p0;
                #pragma unroll
                for (int p = 0; p < 4; ++p) {
                    const float* bp = &lds[buf][basev[p]];
                    float v00 = bp[0],     v01 = bp[1];       // -> ds_read2_b32
                    float v10 = bp[LCOLS], v11 = bp[LCOLS + 1];
                    float top = fmaf(v01, wx1v[p], v00 * wx0v[p]);
                    float bot = fmaf(v11, wx1v[p], v10 * wx0v[p]);
                    o[(size_t)p * Wdim] = fmaf(wy1v[p], bot, wy0v[p] * top);
                }
            };
            auto sampleE = [&](int buf, int c) {
                float* o = out + nbase + (size_t)c * HW + p0;
                #pragma unroll
                for (int p = 0; p < 4; ++p) {
                    float ix = ixs[p], iy = iys[p];
                    float fx = floorf(ix), fy = floorf(iy);
                    int x0i = (int)fx, y0i = (int)fy;
                    float wx1 = ix - fx, wx0 = 1.0f - wx1;
                    float wy1 = iy - fy, wy0 = 1.0f - wy1;
                    float mx0 = ((unsigned)x0i       < (unsigned)Wdim) ? 1.0f : 0.0f;
                    float mx1 = ((unsigned)(x0i + 1) < (unsigned)Wdim) ? 1.0f : 0.0f;
                    float my0 = ((unsigned)y0i       < (unsigned)Hdim) ? 1.0f : 0.0f;
                    float my1 = ((unsigned)(y0i + 1) < (unsigned)Hdim) ? 1.0f : 0.0f;
                    float wxm0 = wx0 * mx0, wxm1 = wx1 * mx1;
                    float wym0 = wy0 * my0, wym1 = wy1 * my1;
                    int lx0 = min(max(x0i - bxw, 0), LCOLS - 1);
                    int lx1 = min(max(x0i + 1 - bxw, 0), LCOLS - 1);
                    int ly0 = min(max(y0i - byw, 0), rn - 1);
                    int ly1 = min(max(y0i + 1 - byw, 0), rn - 1);
                    const float* B = &lds[buf][0];
                    float v00 = B[ly0 * LCOLS + lx0], v01 = B[ly0 * LCOLS + lx1];
                    float v10 = B[ly1 * LCOLS + lx0], v11 = B[ly1 * LCOLS + lx1];
                    float top = fmaf(v01, wxm1, v00 * wxm0);
                    float bot = fmaf(v11, wxm1, v10 * wxm0);
                    o[(size_t)p * Wdim] = fmaf(wym1, bot, wym0 * top);
                }
            };

            const int bA = tt & 1, bB = bA ^ 1;   // c0:bA c1:bB c2:bA next-c0:bB
            __syncthreads();
            stage_ch(gbase + HW, bxw, byw, rn, lds[bB], tid);           // c1
            if (inter) sampleI(bA, 0); else sampleE(bA, 0);
            __syncthreads();
            stage_ch(gbase + 2 * HW, bxw, byw, rn, lds[bA], tid);       // c2
            if (inter) sampleI(bB, 1); else sampleE(bB, 1);
            __syncthreads();
            if (tt < 3)
                stage_ch(gbase, bxws[tt + 1], byws[tt + 1], rns[tt + 1], lds[bB], tid);
            if (inter) sampleI(bA, 2); else sampleE(bA, 2);
        }
    } else {
        // rare slow path: tiles handled sequentially & exactly (block-uniform)
        for (int tt = 0; tt < 4; ++tt) {
            int thp = (thg << 2) + tt;
            int h0 = (thp << 5) + ((tid >> 5) << 2);

            float ixs[4], iys[4];
            float ixb = fmaf((float)w, t0, fmaf((float)h0, t1, Cx));
            float iyb = fmaf((float)w, t3, fmaf((float)h0, t4, Cy));
            #pragma unroll
            for (int p = 0; p < 4; ++p) {
                ixs[p] = fmaf((float)p, t1, ixb);
                iys[p] = fmaf((float)p, t4, iyb);
            }
            // exact per-pixel global gathers
            #pragma unroll
            for (int p = 0; p < 4; ++p) {
                float ix = ixs[p], iy = iys[p];
                float fx = floorf(ix), fy = floorf(iy);
                int ix0 = (int)fx, iy0 = (int)fy;
                float wx1 = ix - fx, wx0 = 1.0f - wx1;
                float wy1 = iy - fy, wy0 = 1.0f - wy1;
                float mx0 = ((unsigned)ix0       < (unsigned)Wdim) ? 1.0f : 0.0f;
                float mx1 = ((unsigned)(ix0 + 1) < (unsigned)Wdim) ? 1.0f : 0.0f;
                float my0 = ((unsigned)iy0       < (unsigned)Hdim) ? 1.0f : 0.0f;
                float my1 = ((unsigned)(iy0 + 1) < (unsigned)Hdim) ? 1.0f : 0.0f;
                int xc0 = min(max(ix0, 0), Wdim - 1);
                int xc1 = min(max(ix0 + 1, 0), Wdim - 1);
                int yc0 = min(max(iy0, 0), Hdim - 1);
                int yc1 = min(max(iy0 + 1, 0), Hdim - 1);
                float w00 = wy0 * wx0 * my0 * mx0;
                float w01 = wy0 * wx1 * my0 * mx1;
                float w10 = wy1 * wx0 * my1 * mx0;
                float w11 = wy1 * wx1 * my1 * mx1;
                int o00 = yc0 * Wdim + xc0, o01 = yc0 * Wdim + xc1;
                int o10 = yc1 * Wdim + xc0, o11 = yc1 * Wdim + xc1;
                #pragma unroll
                for (int c = 0; c < Cdim; ++c) {
                    const float* img = gbase + (size_t)c * HW;
                    float r = fmaf(img[o00], w00, fmaf(img[o01], w01,
                              fmaf(img[o10], w10, img[o11] * w11)));
                    out[nbase + (size_t)c * HW + (size_t)(h0 + p) * Wdim + w] = r;
                }
            }
        }
    }
}

extern "C" void kernel_launch(void* const* d_in, const int* in_sizes, int n_in,
                              void* d_out, int out_size, void* d_ws, size_t ws_size,
                              hipStream_t stream) {
    const float* x     = (const float*)d_in[0];
    const float* theta = (const float*)d_in[1];
    float* out = (float*)d_out;
    float* th  = (float*)d_ws;  // 128*6 floats of scratch

    expm_kernel<<<1, 128, 0, stream>>>(theta, th);

    sample_kernel<<<2048, 256, 0, stream>>>(x, th, out);
}

// Round 15
// 45.058 us; speedup vs baseline: 1.1106x; 1.1106x over previous
//
#include <hip/hip_runtime.h>

#define Ndim 128
#define Cdim 3
#define Hdim 256
#define Wdim 256
#define HW (Hdim * Wdim)
#define MAXNORM_F 5.371920351148152f

#define LCOLS 56     // staged window width (14 x 16B chunks)
#define LROWS 48     // staged window max rows (guard rn <= 48)
#define LBUF  (LCOLS * LROWS)   // 2688 dwords = 10752 B per channel buffer

typedef unsigned int uint32;
typedef float vf4 __attribute__((ext_vector_type(4)));

__device__ __forceinline__ void mm3f(const float a[3][3], const float b[3][3], float c[3][3]) {
    #pragma unroll
    for (int i = 0; i < 3; ++i)
        #pragma unroll
        for (int j = 0; j < 3; ++j) {
            float s = 0.0f;
            #pragma unroll
            for (int k = 0; k < 3; ++k) s = fmaf(a[i][k], b[k][j], s);
            c[i][j] = s;
        }
}

// One thread per batch element: expm of padded 3x3 affine matrix (fp32 Pade-13).
__global__ void expm_kernel(const float* __restrict__ theta, float* __restrict__ thOut) {
    int n = blockIdx.x * blockDim.x + threadIdx.x;
    if (n >= Ndim) return;

    const float b[14] = {6.476475253248e+16f, 3.238237626624e+16f, 7771770303897600.0f,
                         1187353796428800.0f, 129060195264000.0f, 10559470521600.0f,
                         670442572800.0f, 33522128640.0f, 1323241920.0f, 40840800.0f,
                         960960.0f, 16380.0f, 182.0f, 1.0f};

    float A[3][3];
    #pragma unroll
    for (int j = 0; j < 3; ++j) {
        A[0][j] = theta[n * 6 + j];
        A[1][j] = theta[n * 6 + 3 + j];
        A[2][j] = 0.0f;
    }

    float fro2 = 0.0f;
    #pragma unroll
    for (int i = 0; i < 3; ++i)
        #pragma unroll
        for (int j = 0; j < 3; ++j) fro2 = fmaf(A[i][j], A[i][j], fro2);
    float fro = sqrtf(fro2);

    float nsq = fmaxf(0.0f, ceilf(log2f(fro / MAXNORM_F)));
    int k = (int)nsq;
    float sc = exp2f(-nsq);
    #pragma unroll
    for (int i = 0; i < 3; ++i)
        #pragma unroll
        for (int j = 0; j < 3; ++j) A[i][j] *= sc;

    float A2[3][3], A4[3][3], A6[3][3], P[3][3], Wm[3][3], T[3][3], U[3][3], V[3][3];
    mm3f(A, A, A2);
    mm3f(A2, A2, A4);
    mm3f(A4, A2, A6);

    #pragma unroll
    for (int i = 0; i < 3; ++i)
        #pragma unroll
        for (int j = 0; j < 3; ++j)
            P[i][j] = b[13] * A6[i][j] + b[11] * A4[i][j] + b[9] * A2[i][j];
    mm3f(A6, P, T);
    #pragma unroll
    for (int i = 0; i < 3; ++i)
        #pragma unroll
        for (int j = 0; j < 3; ++j)
            Wm[i][j] = T[i][j] + b[7] * A6[i][j] + b[5] * A4[i][j] + b[3] * A2[i][j]
                       + (i == j ? b[1] : 0.0f);
    mm3f(A, Wm, U);

    #pragma unroll
    for (int i = 0; i < 3; ++i)
        #pragma unroll
        for (int j = 0; j < 3; ++j)
            P[i][j] = b[12] * A6[i][j] + b[10] * A4[i][j] + b[8] * A2[i][j];
    mm3f(A6, P, T);
    #pragma unroll
    for (int i = 0; i < 3; ++i)
        #pragma unroll
        for (int j = 0; j < 3; ++j)
            V[i][j] = T[i][j] + b[6] * A6[i][j] + b[4] * A4[i][j] + b[2] * A2[i][j]
                      + (i == j ? b[0] : 0.0f);

    float M[3][6];
    #pragma unroll
    for (int i = 0; i < 3; ++i)
        #pragma unroll
        for (int j = 0; j < 3; ++j) {
            M[i][j]     = U[i][j] + V[i][j];
            M[i][j + 3] = V[i][j] - U[i][j];
        }
    #pragma unroll
    for (int col = 0; col < 3; ++col) {
        int piv = col;
        float best = fabsf(M[col][col]);
        for (int r = col + 1; r < 3; ++r) {
            float v = fabsf(M[r][col]);
            if (v > best) { best = v; piv = r; }
        }
        if (piv != col) {
            #pragma unroll
            for (int j = 0; j < 6; ++j) {
                float t = M[col][j]; M[col][j] = M[piv][j]; M[piv][j] = t;
            }
        }
        float inv = 1.0f / M[col][col];
        #pragma unroll
        for (int j = 0; j < 6; ++j) M[col][j] *= inv;
        #pragma unroll
        for (int r = 0; r < 3; ++r) {
            if (r == col) continue;
            float f = M[r][col];
            #pragma unroll
            for (int j = 0; j < 6; ++j) M[r][j] -= f * M[col][j];
        }
    }
    float R[3][3];
    #pragma unroll
    for (int i = 0; i < 3; ++i)
        #pragma unroll
        for (int j = 0; j < 3; ++j) R[i][j] = M[i][j + 3];

    for (int i = 0; i < 16; ++i) {
        if (i < k) {
            float Rn[3][3];
            mm3f(R, R, Rn);
            #pragma unroll
            for (int a = 0; a < 3; ++a)
                #pragma unroll
                for (int c = 0; c < 3; ++c) R[a][c] = Rn[a][c];
        }
    }

    #pragma unroll
    for (int j = 0; j < 3; ++j) {
        thOut[n * 6 + j]     = (float)R[0][j];
        thOut[n * 6 + 3 + j] = (float)R[1][j];
    }
}

// Fused affine_grid + bilinear grid_sample (zeros padding, align_corners=True).
// Block = 32x32 output tile; 256 threads, each a 1-wide x 4-tall strip.
// Channel ping-pong LDS staging pipeline (R13). R15 change: per-wave LDS
// transpose of results so global stores are dwordx4 — store instructions
// per thread drop 12 -> 3 (VMEM instruction count is the measured binding
// resource: R5's 24->12 gather cut gave 1.37x). Exchange is wave-local
// (wave_barrier + lgkmcnt, no extra block barriers): lane writes its 4
// column-values, reads back a row-segment float4, stores 128B/8-lane rows.
__global__ __launch_bounds__(256) void sample_kernel(const float* __restrict__ x,
                                                     const float* __restrict__ th,
                                                     float* __restrict__ out) {
    __shared__ float lds[2][LBUF];
    __shared__ float xch[4][256];   // per-wave exchange: 8 rows x 32 cols

    // 8x8 tiles/image * 128 images = 8192 blocks; bijective XCD swizzle
    const int nwg_per_xcd = 8192 / 8;
    int bid = blockIdx.x;
    int wgid = (bid & 7) * nwg_per_xcd + (bid >> 3);

    int tw  = wgid & 7;
    int thp = (wgid >> 3) & 7;
    int n   = wgid >> 6;

    int tid  = threadIdx.x;
    int lane = tid & 63;
    int wv   = tid >> 6;                     // wave id (0..3)
    int rh   = (tid >> 5) & 1;               // row-half within wave
    int c32  = tid & 31;                     // column within tile
    int w  = (tw << 5) + c32;                // lane-consecutive column
    int h0 = (thp << 5) + ((tid >> 5) << 2); // 4 rows h0..h0+3

    const float* t = th + n * 6;
    float t0 = t[0], t1 = t[1], t2 = t[2], t3 = t[3], t4 = t[4], t5 = t[5];

    float Cx = 127.5f * (t2 - t0 - t1 + 1.0f);
    float Cy = 127.5f * (t5 - t3 - t4 + 1.0f);

    // block-uniform bounding box of sample coords (pad +-1 fp slack, +1 corner)
    float fwA = (float)(tw << 5),  fwB = fwA + 31.0f;
    float fhA = (float)(thp << 5), fhB = fhA + 31.0f;
    float xlo = fminf(fwA * t0, fwB * t0) + fminf(fhA * t1, fhB * t1) + Cx;
    float xhi = fmaxf(fwA * t0, fwB * t0) + fmaxf(fhA * t1, fhB * t1) + Cx;
    float ylo = fminf(fwA * t3, fwB * t3) + fminf(fhA * t4, fhB * t4) + Cy;
    float yhi = fmaxf(fwA * t3, fwB * t3) + fmaxf(fhA * t4, fhB * t4) + Cy;
    int Xlo = (int)floorf(xlo) - 1, Xhi = (int)floorf(xhi) + 2;
    int Ylo = (int)floorf(ylo) - 1, Yhi = (int)floorf(yhi) + 2;
    int cn = Xhi - Xlo + 1;
    int rn = Yhi - Ylo + 1;

    size_t nbase = (size_t)n * Cdim * HW;

    // strip sample coords: px p at (w, h0+p)
    float ixs[4], iys[4];
    float ixb = fmaf((float)w, t0, fmaf((float)h0, t1, Cx));
    float iyb = fmaf((float)w, t3, fmaf((float)h0, t4, Cy));
    #pragma unroll
    for (int p = 0; p < 4; ++p) {
        ixs[p] = fmaf((float)p, t1, ixb);
        iys[p] = fmaf((float)p, t4, iyb);
    }

    bool fast = (cn <= 52) && (rn <= LROWS) && (rn >= 1) && (cn >= 1);

    if (fast) {
        int bxw = (min(max(Xlo, 0), Wdim - LCOLS)) & ~3;  // 16B-aligned base col
        int byw = min(max(Ylo, 0), Hdim - rn);
        int totc = 14 * rn;                               // 16B chunks per channel
        const float* gbase = x + nbase;

        auto stage = [&](int ch, int buf) {
            #pragma unroll
            for (int it = 0; it < 3; ++it) {
                int k = (it << 8) + tid;
                if (k < totc) {
                    int row = k / 14;
                    int col = k - row * 14;
                    const float* gp = gbase + (size_t)ch * HW
                                    + ((byw + row) << 8) + bxw + (col << 2);
                    __builtin_amdgcn_global_load_lds(
                        (const __attribute__((address_space(1))) uint32*)gp,
                        (__attribute__((address_space(3))) uint32*)
                            ((uint32*)&lds[buf][0] + ((size_t)k << 2)),
                        16, 0, 0);
                }
            }
        };

        bool interior = (Xlo >= 0) && (Xhi <= Wdim - 1) && (Ylo >= 0) && (Yhi <= Hdim - 1);

        stage(0, 0);

        // precompute per-pixel params while c0 is in flight
        int   basev[4];
        float wx1v[4], wx0v[4], wy1v[4], wy0v[4];
        if (interior) {
            #pragma unroll
            for (int p = 0; p < 4; ++p) {
                float ix = ixs[p], iy = iys[p];
                float fx = floorf(ix), fy = floorf(iy);
                wx1v[p] = ix - fx; wx0v[p] = 1.0f - wx1v[p];
                wy1v[p] = iy - fy; wy0v[p] = 1.0f - wy1v[p];
                basev[p] = ((int)fy - byw) * LCOLS + ((int)fx - bxw);
            }
        }

        auto sampleI = [&](int buf, float res[4]) {
            #pragma unroll
            for (int p = 0; p < 4; ++p) {
                const float* bp = &lds[buf][basev[p]];
                float v00 = bp[0],     v01 = bp[1];        // -> ds_read2_b32
                float v10 = bp[LCOLS], v11 = bp[LCOLS + 1];
                float top = fmaf(v01, wx1v[p], v00 * wx0v[p]);
                float bot = fmaf(v11, wx1v[p], v10 * wx0v[p]);
                res[p] = fmaf(wy1v[p], bot, wy0v[p] * top);
            }
        };

        auto sampleE = [&](int buf, float res[4]) {
            #pragma unroll
            for (int p = 0; p < 4; ++p) {
                float ix = ixs[p], iy = iys[p];
                float fx = floorf(ix), fy = floorf(iy);
                int x0i = (int)fx, y0i = (int)fy;
                float wx1 = ix - fx, wx0 = 1.0f - wx1;
                float wy1 = iy - fy, wy0 = 1.0f - wy1;
                float mx0 = ((unsigned)x0i       < (unsigned)Wdim) ? 1.0f : 0.0f;
                float mx1 = ((unsigned)(x0i + 1) < (unsigned)Wdim) ? 1.0f : 0.0f;
                float my0 = ((unsigned)y0i       < (unsigned)Hdim) ? 1.0f : 0.0f;
                float my1 = ((unsigned)(y0i + 1) < (unsigned)Hdim) ? 1.0f : 0.0f;
                float wxm0 = wx0 * mx0, wxm1 = wx1 * mx1;
                float wym0 = wy0 * my0, wym1 = wy1 * my1;

                int lx0 = min(max(x0i - bxw, 0), LCOLS - 1);
                int lx1 = min(max(x0i + 1 - bxw, 0), LCOLS - 1);
                int ly0 = min(max(y0i - byw, 0), rn - 1);
                int ly1 = min(max(y0i + 1 - byw, 0), rn - 1);
                const float* B = &lds[buf][0];
                float v00 = B[ly0 * LCOLS + lx0], v01 = B[ly0 * LCOLS + lx1];
                float v10 = B[ly1 * LCOLS + lx0], v11 = B[ly1 * LCOLS + lx1];
                float top = fmaf(v01, wxm1, v00 * wxm0);
                float bot = fmaf(v11, wxm1, v10 * wxm0);
                res[p] = fmaf(wym1, bot, wym0 * top);
            }
        };

        // wave-local transpose: 12 scalar stores -> 3 dwordx4 stores/thread
        int rl = lane >> 3;            // row-local 0..7
        int g  = lane & 7;             // 16B column group
        size_t orow = (size_t)((thp << 5) + (wv << 3) + rl) * Wdim + (tw << 5) + (g << 2);

        auto flushC = [&](const float res[4], int c) {
            #pragma unroll
            for (int p = 0; p < 4; ++p)
                xch[wv][((rh << 2) + p) * 32 + c32] = res[p];
            __builtin_amdgcn_wave_barrier();
            asm volatile("s_waitcnt lgkmcnt(0)" ::: "memory");
            vf4 v = *(const vf4*)&xch[wv][(rl << 5) + (g << 2)];
            __builtin_amdgcn_wave_barrier();
            *(vf4*)(out + nbase + (size_t)c * HW + orow) = v;
        };

        float res[4];
        __syncthreads();              // waits c0 (compiler vmcnt drain)
        stage(1, 1);                  // issue c1 while sampling c0
        if (interior) sampleI(0, res); else sampleE(0, res);
        flushC(res, 0);
        __syncthreads();              // waits c1
        stage(2, 0);                  // issue c2 while sampling c1
        if (interior) sampleI(1, res); else sampleE(1, res);
        flushC(res, 1);
        __syncthreads();              // waits c2
        if (interior) sampleI(0, res); else sampleE(0, res);
        flushC(res, 2);
    } else {
        // exact fallback: per-pixel global gathers (block-uniform branch)
        const float* img0 = x + nbase;
        #pragma unroll
        for (int p = 0; p < 4; ++p) {
            float ix = ixs[p], iy = iys[p];
            float fx = floorf(ix), fy = floorf(iy);
            int ix0 = (int)fx, iy0 = (int)fy;
            float wx1 = ix - fx, wx0 = 1.0f - wx1;
            float wy1 = iy - fy, wy0 = 1.0f - wy1;
            float mx0 = ((unsigned)ix0       < (unsigned)Wdim) ? 1.0f : 0.0f;
            float mx1 = ((unsigned)(ix0 + 1) < (unsigned)Wdim) ? 1.0f : 0.0f;
            float my0 = ((unsigned)iy0       < (unsigned)Hdim) ? 1.0f : 0.0f;
            float my1 = ((unsigned)(iy0 + 1) < (unsigned)Hdim) ? 1.0f : 0.0f;
            int xc0 = min(max(ix0, 0), Wdim - 1);
            int xc1 = min(max(ix0 + 1, 0), Wdim - 1);
            int yc0 = min(max(iy0, 0), Hdim - 1);
            int yc1 = min(max(iy0 + 1, 0), Hdim - 1);
            float w00 = wy0 * wx0 * my0 * mx0;
            float w01 = wy0 * wx1 * my0 * mx1;
            float w10 = wy1 * wx0 * my1 * mx0;
            float w11 = wy1 * wx1 * my1 * mx1;
            int o00 = yc0 * Wdim + xc0, o01 = yc0 * Wdim + xc1;
            int o10 = yc1 * Wdim + xc0, o11 = yc1 * Wdim + xc1;
            #pragma unroll
            for (int c = 0; c < Cdim; ++c) {
                const float* img = img0 + (size_t)c * HW;
                float r = fmaf(img[o00], w00, fmaf(img[o01], w01,
                          fmaf(img[o10], w10, img[o11] * w11)));
                out[nbase + (size_t)c * HW + (size_t)(h0 + p) * Wdim + w] = r;
            }
        }
    }
}

extern "C" void kernel_launch(void* const* d_in, const int* in_sizes, int n_in,
                              void* d_out, int out_size, void* d_ws, size_t ws_size,
                              hipStream_t stream) {
    const float* x     = (const float*)d_in[0];
    const float* theta = (const float*)d_in[1];
    float* out = (float*)d_out;
    float* th  = (float*)d_ws;  // 128*6 floats of scratch

    expm_kernel<<<1, 128, 0, stream>>>(theta, th);

    sample_kernel<<<8192, 256, 0, stream>>>(x, th, out);
}

// Round 16
// 40.814 us; speedup vs baseline: 1.2261x; 1.1040x over previous
//
#include <hip/hip_runtime.h>

#define Ndim 128
#define Cdim 3
#define Hdim 256
#define Wdim 256
#define HW (Hdim * Wdim)
#define MAXNORM_F 5.371920351148152f

typedef float vf2 __attribute__((ext_vector_type(2)));
typedef unsigned int uint32;

__device__ __forceinline__ void mm3f(const float a[3][3], const float b[3][3], float c[3][3]) {
    #pragma unroll
    for (int i = 0; i < 3; ++i)
        #pragma unroll
        for (int j = 0; j < 3; ++j) {
            float s = 0.0f;
            #pragma unroll
            for (int k = 0; k < 3; ++k) s = fmaf(a[i][k], b[k][j], s);
            c[i][j] = s;
        }
}

// One thread per batch element: expm of padded 3x3 affine matrix (fp32 Pade-13).
__global__ void expm_kernel(const float* __restrict__ theta, float* __restrict__ thOut) {
    int n = blockIdx.x * blockDim.x + threadIdx.x;
    if (n >= Ndim) return;

    const float b[14] = {6.476475253248e+16f, 3.238237626624e+16f, 7771770303897600.0f,
                         1187353796428800.0f, 129060195264000.0f, 10559470521600.0f,
                         670442572800.0f, 33522128640.0f, 1323241920.0f, 40840800.0f,
                         960960.0f, 16380.0f, 182.0f, 1.0f};

    float A[3][3];
    #pragma unroll
    for (int j = 0; j < 3; ++j) {
        A[0][j] = theta[n * 6 + j];
        A[1][j] = theta[n * 6 + 3 + j];
        A[2][j] = 0.0f;
    }

    float fro2 = 0.0f;
    #pragma unroll
    for (int i = 0; i < 3; ++i)
        #pragma unroll
        for (int j = 0; j < 3; ++j) fro2 = fmaf(A[i][j], A[i][j], fro2);
    float fro = sqrtf(fro2);

    float nsq = fmaxf(0.0f, ceilf(log2f(fro / MAXNORM_F)));
    int k = (int)nsq;
    float sc = exp2f(-nsq);
    #pragma unroll
    for (int i = 0; i < 3; ++i)
        #pragma unroll
        for (int j = 0; j < 3; ++j) A[i][j] *= sc;

    float A2[3][3], A4[3][3], A6[3][3], P[3][3], Wm[3][3], T[3][3], U[3][3], V[3][3];
    mm3f(A, A, A2);
    mm3f(A2, A2, A4);
    mm3f(A4, A2, A6);

    #pragma unroll
    for (int i = 0; i < 3; ++i)
        #pragma unroll
        for (int j = 0; j < 3; ++j)
            P[i][j] = b[13] * A6[i][j] + b[11] * A4[i][j] + b[9] * A2[i][j];
    mm3f(A6, P, T);
    #pragma unroll
    for (int i = 0; i < 3; ++i)
        #pragma unroll
        for (int j = 0; j < 3; ++j)
            Wm[i][j] = T[i][j] + b[7] * A6[i][j] + b[5] * A4[i][j] + b[3] * A2[i][j]
                       + (i == j ? b[1] : 0.0f);
    mm3f(A, Wm, U);

    #pragma unroll
    for (int i = 0; i < 3; ++i)
        #pragma unroll
        for (int j = 0; j < 3; ++j)
            P[i][j] = b[12] * A6[i][j] + b[10] * A4[i][j] + b[8] * A2[i][j];
    mm3f(A6, P, T);
    #pragma unroll
    for (int i = 0; i < 3; ++i)
        #pragma unroll
        for (int j = 0; j < 3; ++j)
            V[i][j] = T[i][j] + b[6] * A6[i][j] + b[4] * A4[i][j] + b[2] * A2[i][j]
                      + (i == j ? b[0] : 0.0f);

    float M[3][6];
    #pragma unroll
    for (int i = 0; i < 3; ++i)
        #pragma unroll
        for (int j = 0; j < 3; ++j) {
            M[i][j]     = U[i][j] + V[i][j];
            M[i][j + 3] = V[i][j] - U[i][j];
        }
    #pragma unroll
    for (int col = 0; col < 3; ++col) {
        int piv = col;
        float best = fabsf(M[col][col]);
        for (int r = col + 1; r < 3; ++r) {
            float v = fabsf(M[r][col]);
            if (v > best) { best = v; piv = r; }
        }
        if (piv != col) {
            #pragma unroll
            for (int j = 0; j < 6; ++j) {
                float t = M[col][j]; M[col][j] = M[piv][j]; M[piv][j] = t;
            }
        }
        float inv = 1.0f / M[col][col];
        #pragma unroll
        for (int j = 0; j < 6; ++j) M[col][j] *= inv;
        #pragma unroll
        for (int r = 0; r < 3; ++r) {
            if (r == col) continue;
            float f = M[r][col];
            #pragma unroll
            for (int j = 0; j < 6; ++j) M[r][j] -= f * M[col][j];
        }
    }
    float R[3][3];
    #pragma unroll
    for (int i = 0; i < 3; ++i)
        #pragma unroll
        for (int j = 0; j < 3; ++j) R[i][j] = M[i][j + 3];

    for (int i = 0; i < 16; ++i) {
        if (i < k) {
            float Rn[3][3];
            mm3f(R, R, Rn);
            #pragma unroll
            for (int a = 0; a < 3; ++a)
                #pragma unroll
                for (int c = 0; c < 3; ++c) R[a][c] = Rn[a][c];
        }
    }

    #pragma unroll
    for (int j = 0; j < 3; ++j) {
        thOut[n * 6 + j]     = (float)R[0][j];
        thOut[n * 6 + 3 + j] = (float)R[1][j];
    }
}

// Fused affine_grid + bilinear grid_sample (zeros padding, align_corners=True).
// Best-measured configuration (R10, 40.9us): block = 32x32 output tile;
// 256 threads, each a 1-wide x 4-tall strip (lane lx stride 1 -> minimal
// bank aliasing). Phase 1: stage block-uniform window (56 cols x rn+1 rows
// x 3 ch, 40960B LDS) via global_load_lds dwordx4, linear dest, layout
// [row][ch][56]. Phase 2: interior blocks mask/clamp-free with paired reads
// (ds_read2_b32); edge blocks per-corner-clamped (displaced slot => weight
// 0). Non-fast blocks: exact global-gather fallback. Bijective XCD swizzle.
__global__ __launch_bounds__(256) void sample_kernel(const float* __restrict__ x,
                                                     const float* __restrict__ th,
                                                     float* __restrict__ out) {
    __shared__ float lds[10240];  // 2560 chunks * 16B = 40960 B

    const int nwg_per_xcd = 8192 / 8;
    int bid = blockIdx.x;
    int wgid = (bid & 7) * nwg_per_xcd + (bid >> 3);

    int tw  = wgid & 7;
    int thp = (wgid >> 3) & 7;
    int n   = wgid >> 6;

    int tid = threadIdx.x;
    int w  = (tw << 5) + (tid & 31);        // lane-consecutive column
    int h0 = (thp << 5) + ((tid >> 5) << 2); // 4 rows h0..h0+3

    const float* t = th + n * 6;
    float t0 = t[0], t1 = t[1], t2 = t[2], t3 = t[3], t4 = t[4], t5 = t[5];

    float Cx = 127.5f * (t2 - t0 - t1 + 1.0f);
    float Cy = 127.5f * (t5 - t3 - t4 + 1.0f);

    float fwA = (float)(tw << 5),  fwB = fwA + 31.0f;
    float fhA = (float)(thp << 5), fhB = fhA + 31.0f;
    float xlo = fminf(fwA * t0, fwB * t0) + fminf(fhA * t1, fhB * t1) + Cx;
    float xhi = fmaxf(fwA * t0, fwB * t0) + fmaxf(fhA * t1, fhB * t1) + Cx;
    float ylo = fminf(fwA * t3, fwB * t3) + fminf(fhA * t4, fhB * t4) + Cy;
    float yhi = fmaxf(fwA * t3, fwB * t3) + fmaxf(fhA * t4, fhB * t4) + Cy;
    int Xlo = (int)floorf(xlo) - 1, Xhi = (int)floorf(xhi) + 2;
    int Ylo = (int)floorf(ylo) - 1, Yhi = (int)floorf(yhi) + 2;
    int cn = Xhi - Xlo + 1;
    int rn = Yhi - Ylo + 1;

    size_t nbase = (size_t)n * Cdim * HW;

    float ixs[4], iys[4];
    float ixb = fmaf((float)w, t0, fmaf((float)h0, t1, Cx));
    float iyb = fmaf((float)w, t3, fmaf((float)h0, t4, Cy));
    #pragma unroll
    for (int p = 0; p < 4; ++p) {
        ixs[p] = fmaf((float)p, t1, ixb);
        iys[p] = fmaf((float)p, t4, iyb);
    }

    bool fast = (cn <= 52) && (rn <= 55) && (rn >= 1) && (cn >= 1);

    if (fast) {
        int bxw = (min(max(Xlo, 0), Wdim - 56)) & ~3;  // 16B-aligned window base col
        int byw = min(max(Ylo, 0), Hdim - rn);

        int totc  = 42 * (rn + 1);           // 16B chunks (42 = 3ch * 14 chunks/row)
        int iters = (totc + 255) >> 8;       // <= 10
        const float* gbase = x + nbase;
        for (int it = 0; it < iters; ++it) {
            int c = (it << 8) + tid;
            int row = c / 42;
            int rem = c - row * 42;
            row = min(row, rn);                       // overshoot -> re-stage last row
            int ch   = rem / 14;
            int colc = rem - ch * 14;
            int srow = min(byw + row, Hdim - 1);      // extra row clamped in-image
            const float* gp = gbase + (size_t)ch * HW + (srow << 8) + bxw + (colc << 2);
            __builtin_amdgcn_global_load_lds(
                (const __attribute__((address_space(1))) uint32*)gp,
                (__attribute__((address_space(3))) uint32*)((uint32*)lds + ((size_t)c << 2)),
                16, 0, 0);
        }
        __syncthreads();

        bool interior = (Xlo >= 0) && (Xhi <= Wdim - 1) && (Ylo >= 0) && (Yhi <= Hdim - 1);

        float res[4][3];
        if (interior) {
            #pragma unroll
            for (int p = 0; p < 4; ++p) {
                float ix = ixs[p], iy = iys[p];
                float fx = floorf(ix), fy = floorf(iy);
                int x0i = (int)fx, y0i = (int)fy;
                float wx1 = ix - fx, wx0 = 1.0f - wx1;
                float wy1 = iy - fy, wy0 = 1.0f - wy1;

                int lx = x0i - bxw;              // in [0,54]
                int ly = y0i - byw;              // in [0,rn-2]
                int base = ly * 168 + lx;        // [row][ch][56] dword index
                #pragma unroll
                for (int c = 0; c < Cdim; ++c) {
                    const float* bp = lds + base + c * 56;
                    float v00 = bp[0],   v01 = bp[1];     // fuse -> ds_read2_b32
                    float v10 = bp[168], v11 = bp[169];   // fuse -> ds_read2_b32
                    float top = fmaf(v01, wx1, v00 * wx0);
                    float bot = fmaf(v11, wx1, v10 * wx0);
                    res[p][c] = fmaf(wy1, bot, wy0 * top);
                }
            }
        } else {
            #pragma unroll
            for (int p = 0; p < 4; ++p) {
                float ix = ixs[p], iy = iys[p];
                float fx = floorf(ix), fy = floorf(iy);
                int x0i = (int)fx, y0i = (int)fy;
                float wx1 = ix - fx, wx0 = 1.0f - wx1;
                float wy1 = iy - fy, wy0 = 1.0f - wy1;
                float mx0 = ((unsigned)x0i       < (unsigned)Wdim) ? 1.0f : 0.0f;
                float mx1 = ((unsigned)(x0i + 1) < (unsigned)Wdim) ? 1.0f : 0.0f;
                float my0 = ((unsigned)y0i       < (unsigned)Hdim) ? 1.0f : 0.0f;
                float my1 = ((unsigned)(y0i + 1) < (unsigned)Hdim) ? 1.0f : 0.0f;
                float wxm0 = wx0 * mx0, wxm1 = wx1 * mx1;
                float wym0 = wy0 * my0, wym1 = wy1 * my1;

                int lx0 = min(max(x0i - bxw, 0), 55);
                int lx1 = min(max(x0i + 1 - bxw, 0), 55);
                int ly0 = min(max(y0i - byw, 0), rn);
                int ly1 = min(max(y0i + 1 - byw, 0), rn);
                int r0 = ly0 * 168, r1 = ly1 * 168;
                #pragma unroll
                for (int c = 0; c < Cdim; ++c) {
                    int b0 = r0 + c * 56;
                    int b1 = r1 + c * 56;
                    float v00 = lds[b0 + lx0], v01 = lds[b0 + lx1];
                    float v10 = lds[b1 + lx0], v11 = lds[b1 + lx1];
                    float top = fmaf(v01, wxm1, v00 * wxm0);
                    float bot = fmaf(v11, wxm1, v10 * wxm0);
                    res[p][c] = fmaf(wym1, bot, wym0 * top);
                }
            }
        }

        size_t p0 = (size_t)h0 * Wdim + w;
        #pragma unroll
        for (int c = 0; c < Cdim; ++c)
            #pragma unroll
            for (int p = 0; p < 4; ++p)
                __builtin_nontemporal_store(res[p][c],
                    out + nbase + (size_t)c * HW + p0 + (size_t)p * Wdim);
    } else {
        const float* img0 = x + nbase;
        #pragma unroll
        for (int p = 0; p < 4; ++p) {
            float ix = ixs[p], iy = iys[p];
            float fx = floorf(ix), fy = floorf(iy);
            int ix0 = (int)fx, iy0 = (int)fy;
            float wx1 = ix - fx, wx0 = 1.0f - wx1;
            float wy1 = iy - fy, wy0 = 1.0f - wy1;
            float mx0 = ((unsigned)ix0       < (unsigned)Wdim) ? 1.0f : 0.0f;
            float mx1 = ((unsigned)(ix0 + 1) < (unsigned)Wdim) ? 1.0f : 0.0f;
            float my0 = ((unsigned)iy0       < (unsigned)Hdim) ? 1.0f : 0.0f;
            float my1 = ((unsigned)(iy0 + 1) < (unsigned)Hdim) ? 1.0f : 0.0f;
            int xc0 = min(max(ix0, 0), Wdim - 1);
            int xc1 = min(max(ix0 + 1, 0), Wdim - 1);
            int yc0 = min(max(iy0, 0), Hdim - 1);
            int yc1 = min(max(iy0 + 1, 0), Hdim - 1);
            float w00 = wy0 * wx0 * my0 * mx0;
            float w01 = wy0 * wx1 * my0 * mx1;
            float w10 = wy1 * wx0 * my1 * mx0;
            float w11 = wy1 * wx1 * my1 * mx1;
            int o00 = yc0 * Wdim + xc0, o01 = yc0 * Wdim + xc1;
            int o10 = yc1 * Wdim + xc0, o11 = yc1 * Wdim + xc1;
            #pragma unroll
            for (int c = 0; c < Cdim; ++c) {
                const float* img = img0 + (size_t)c * HW;
                float r = fmaf(img[o00], w00, fmaf(img[o01], w01,
                          fmaf(img[o10], w10, img[o11] * w11)));
                out[nbase + (size_t)c * HW + (size_t)(h0 + p) * Wdim + w] = r;
            }
        }
    }
}

extern "C" void kernel_launch(void* const* d_in, const int* in_sizes, int n_in,
                              void* d_out, int out_size, void* d_ws, size_t ws_size,
                              hipStream_t stream) {
    const float* x     = (const float*)d_in[0];
    const float* theta = (const float*)d_in[1];
    float* out = (float*)d_out;
    float* th  = (float*)d_ws;  // 128*6 floats of scratch

    expm_kernel<<<1, 128, 0, stream>>>(theta, th);

    int nblocks = 8192;
    sample_kernel<<<nblocks, 256, 0, stream>>>(x, th, out);
}